// Round 1
// baseline (352.381 us; speedup 1.0000x reference)
//
#include <hip/hip_runtime.h>
#include <hip/hip_bf16.h>

typedef __bf16 bf16;
typedef bf16  bf16x8 __attribute__((ext_vector_type(8)));
typedef bf16  bf16x4 __attribute__((ext_vector_type(4)));
typedef float f32x4  __attribute__((ext_vector_type(4)));
typedef int   i32x4  __attribute__((ext_vector_type(4)));

#define MFMA16(a,b,c) __builtin_amdgcn_mfma_f32_16x16x32_bf16((a),(b),(c),0,0,0)

#define GLDS16(gp, lp) __builtin_amdgcn_global_load_lds( \
    (const __attribute__((address_space(1))) void*)(void*)(gp), \
    (__attribute__((address_space(3))) void*)(lp), 16, 0, 0)

static __device__ __forceinline__ bf16x8 lds_frag(const char* p){
  i32x4 v = *(const i32x4*)p;
  return __builtin_bit_cast(bf16x8, v);
}
static __device__ __forceinline__ bf16x8 g_frag(const bf16* p){
  i32x4 v = *(const i32x4*)p;
  return __builtin_bit_cast(bf16x8, v);
}

// ---------------- min/max reduction (order-independent -> deterministic) ---
__device__ __forceinline__ unsigned fmap(float f){
  unsigned u = __float_as_uint(f);
  return (u & 0x80000000u) ? ~u : (u | 0x80000000u);
}
__device__ __forceinline__ float funmap(unsigned m){
  unsigned u = (m & 0x80000000u) ? (m & 0x7FFFFFFFu) : ~m;
  return __uint_as_float(u);
}

__global__ void init_mm(unsigned* mm){
  if (threadIdx.x == 0){
    mm[0] = 0xFFFFFFFFu; mm[1] = 0u;   // w_qkv min,max (mapped)
    mm[2] = 0xFFFFFFFFu; mm[3] = 0u;   // w_out min,max
  }
}

__global__ void minmax_k(const float* __restrict__ w, int n, unsigned* __restrict__ mm){
  __shared__ unsigned smn[256], smx[256];
  int tid = threadIdx.x;
  unsigned lmn = 0xFFFFFFFFu, lmx = 0u;
  for (int i = blockIdx.x * blockDim.x + tid; i < n; i += gridDim.x * blockDim.x){
    unsigned u = fmap(w[i]);
    lmn = min(lmn, u); lmx = max(lmx, u);
  }
  smn[tid] = lmn; smx[tid] = lmx;
  __syncthreads();
  for (int s = 128; s > 0; s >>= 1){
    if (tid < s){
      smn[tid] = min(smn[tid], smn[tid + s]);
      smx[tid] = max(smx[tid], smx[tid + s]);
    }
    __syncthreads();
  }
  if (tid == 0){ atomicMin(&mm[0], smn[0]); atomicMax(&mm[1], smx[0]); }
}

// ------------- fake-quant dequant + transpose + cast to bf16 ---------------
// w: R x C (f32) -> wt: C x R (bf16), faithful quantize_bits(w, 8)
__global__ void dq_t(const float* __restrict__ w, bf16* __restrict__ wt,
                     int R, int C, const unsigned* __restrict__ mm){
  __shared__ float t[32][33];
  float xmin = funmap(mm[0]);
  float xmax = funmap(mm[1]);
  float scale = (xmax - xmin) / 255.0f;     // (qmax+1e-8) rounds to 255.0f in f32
  float denom = scale + 1e-8f;
  int ct = blockIdx.x * 32, rt = blockIdx.y * 32;
  int tx = threadIdx.x, ty = threadIdx.y;   // 32 x 8
#pragma unroll
  for (int p = 0; p < 4; ++p){
    int r = rt + p * 8 + ty;
    float x = w[(size_t)r * C + ct + tx];
    float q = rintf(fminf(fmaxf((x - xmin) / denom, 0.0f), 255.0f));
    t[p * 8 + ty][tx] = q * scale + xmin;
  }
  __syncthreads();
#pragma unroll
  for (int p = 0; p < 4; ++p){
    int c = p * 8 + ty;
    wt[(size_t)(ct + c) * R + rt + tx] = (bf16)t[tx][c];
  }
}

// ---------------- cast x (f32) -> bf16, vectorized x4 ----------------------
__global__ void cast_x(const float* __restrict__ x, bf16* __restrict__ xb, int n4){
  int i = blockIdx.x * 256 + threadIdx.x;
  if (i < n4){
    f32x4 v = *(const f32x4*)(x + (size_t)i * 4);
    bf16x4 o = { (bf16)v.x, (bf16)v.y, (bf16)v.z, (bf16)v.w };
    *(bf16x4*)(xb + (size_t)i * 4) = o;
  }
}

// ---------------- rope tables ----------------------------------------------
__global__ void sincos_k(float* __restrict__ sintab, float* __restrict__ costab){
  int idx = blockIdx.x * 256 + threadIdx.x;   // s*32 + i, 65536 total
  int i = idx & 31, s = idx >> 5;
  float invf = powf(10000.0f, -(float)i / 32.0f);
  float fr = (float)s * invf;
  sintab[idx] = sinf(fr);
  costab[idx] = cosf(fr);
}

// ------------- rope + reshape QKV(f32) -> Qr,Kr (B,H,S,D) bf16 -------------
__global__ void rope_qk(const float* __restrict__ qkv,
                        const float* __restrict__ sintab, const float* __restrict__ costab,
                        bf16* __restrict__ Qr, bf16* __restrict__ Kr){
  int idx = blockIdx.x * 256 + threadIdx.x;   // (bh*2048 + s)*32 + i
  int i  = idx & 31;
  int s  = (idx >> 5) & 2047;
  int bh = idx >> 16;
  int b = bh >> 4, h = bh & 15;
  const float* row = qkv + (size_t)(b * 2048 + s) * 3072 + h * 64;
  float q1 = row[i],        q2 = row[32 + i];
  float k1 = row[1024 + i], k2 = row[1024 + 32 + i];
  float sn = sintab[s * 32 + i], cs = costab[s * 32 + i];
  size_t o = ((size_t)bh * 2048 + s) * 64 + i;
  Qr[o]      = (bf16)(q1 * cs - q2 * sn);
  Qr[o + 32] = (bf16)(q1 * sn + q2 * cs);
  Kr[o]      = (bf16)(k1 * cs - k2 * sn);
  Kr[o + 32] = (bf16)(k1 * sn + k2 * cs);
}

// ------------- V transpose: QKV(f32) -> Vt (B,H,D,S) bf16 ------------------
__global__ void vtrans(const float* __restrict__ qkv, bf16* __restrict__ Vt){
  __shared__ float t[64][65];
  int bh = blockIdx.x >> 5;
  int st = (blockIdx.x & 31) * 64;
  int b = bh >> 4, h = bh & 15;
  int tx = threadIdx.x & 63, ty4 = threadIdx.x >> 6;
#pragma unroll
  for (int p = 0; p < 16; ++p){
    int s = p * 4 + ty4;
    t[s][tx] = qkv[(size_t)(b * 2048 + st + s) * 3072 + 2048 + h * 64 + tx];
  }
  __syncthreads();
#pragma unroll
  for (int p = 0; p < 16; ++p){
    int d = p * 4 + ty4;
    Vt[((size_t)bh * 64 + d) * 2048 + st + tx] = (bf16)t[tx][d];
  }
}

// ---------------- bf16 MFMA GEMM, C = A * Bt^T -----------------------------
// A: M x K row-major bf16 ; Bt: N x K row-major bf16 ; C: M x N f32
// 128x128 tile, BK=64, 4 waves (2x2 of 64x64), global_load_lds staging with
// XOR chunk swizzle (2-way bank conflicts = free).
__global__ __launch_bounds__(256, 2) void gemm_bt(
    const bf16* __restrict__ A, const bf16* __restrict__ Bt,
    float* __restrict__ C, int M, int N, int K)
{
  __shared__ __align__(16) char lds[32768];   // [0,16K) = A tile, [16K,32K) = B tile
  int nbx = N >> 7;
  int bid = blockIdx.x;
  int nwg = gridDim.x;
  if ((nwg & 7) == 0){ int q = nwg >> 3; bid = (bid & 7) * q + (bid >> 3); }  // XCD swizzle
  int row0 = (bid / nbx) << 7;
  int col0 = (bid % nbx) << 7;
  int tid = threadIdx.x, lane = tid & 63, wid = tid >> 6;
  int wr = (wid >> 1) * 64, wc = (wid & 1) * 64;
  int lr = lane & 15, g = lane >> 4;

  // fragment read offsets (bytes), chunk XOR-swizzled
  int aoff[2][4], boff[2][4];
#pragma unroll
  for (int kk = 0; kk < 2; ++kk){
#pragma unroll
    for (int m = 0; m < 4; ++m){
      int ra = wr + m * 16 + lr;
      aoff[kk][m] = ra * 128 + ((((kk * 4 + g) ^ ((ra >> 1) & 7))) << 4);
      int rb = wc + m * 16 + lr;
      boff[kk][m] = 16384 + rb * 128 + ((((kk * 4 + g) ^ ((rb >> 1) & 7))) << 4);
    }
  }

  // staging source pointers (pre-swizzled global chunks -> linear LDS dest)
  const bf16* pA[4]; const bf16* pB[4]; int loff[4];
#pragma unroll
  for (int is = 0; is < 4; ++is){
    int f = is * 4096 + wid * 1024 + lane * 16;   // byte index in 16KB tile
    int r = f >> 7, c = (f >> 4) & 7;
    int cg = c ^ ((r >> 1) & 7);
    pA[is] = A  + (size_t)(row0 + r) * K + cg * 8;
    pB[is] = Bt + (size_t)(col0 + r) * K + cg * 8;
    loff[is] = is * 4096 + wid * 1024;            // wave-uniform LDS base
  }

  f32x4 acc[4][4] = {};
  for (int kt = 0; kt < K; kt += 64){
    __syncthreads();
#pragma unroll
    for (int is = 0; is < 4; ++is){
      GLDS16(pA[is] + kt, lds + loff[is]);
      GLDS16(pB[is] + kt, lds + 16384 + loff[is]);
    }
    __syncthreads();
#pragma unroll
    for (int kk = 0; kk < 2; ++kk){
      bf16x8 af[4], bfb[4];
#pragma unroll
      for (int m = 0; m < 4; ++m) af[m] = lds_frag(lds + aoff[kk][m]);
#pragma unroll
      for (int n = 0; n < 4; ++n) bfb[n] = lds_frag(lds + boff[kk][n]);
#pragma unroll
      for (int m = 0; m < 4; ++m)
#pragma unroll
        for (int n = 0; n < 4; ++n)
          acc[m][n] = MFMA16(af[m], bfb[n], acc[m][n]);
    }
  }

  // epilogue: D layout col=lane&15, row=(lane>>4)*4+reg   [m89-verified]
#pragma unroll
  for (int m = 0; m < 4; ++m){
    int row = row0 + wr + m * 16 + g * 4;
#pragma unroll
    for (int n = 0; n < 4; ++n){
      int col = col0 + wc + n * 16 + lr;
      float* cp = C + (size_t)row * N + col;
#pragma unroll
      for (int r = 0; r < 4; ++r)
        cp[(size_t)r * N] = acc[m][n][r];
    }
  }
}

// ---------------- flash attention ------------------------------------------
// grid: 32 (b*h) x 32 (q-tiles of 64); block 256 = 4 waves; wave = 16 queries.
// Q,K: (BH, S, D) bf16 ; Vt: (BH, D, S) bf16 ; AO: (B*S, E) bf16
__global__ __launch_bounds__(256, 2) void attn_k(
    const bf16* __restrict__ Q, const bf16* __restrict__ K,
    const bf16* __restrict__ Vt, bf16* __restrict__ AO)
{
  __shared__ __align__(16) bf16 P[4][16][72];   // per-wave P buffer, padded stride
  int bid = blockIdx.x;
  int bh = bid >> 5, qt = bid & 31;
  int b = bh >> 4, h = bh & 15;
  int tid = threadIdx.x, lane = tid & 63, wid = tid >> 6;
  int lr = lane & 15, g = lane >> 4;
  int q0 = qt * 64 + wid * 16;

  const bf16* Qb = Q  + ((size_t)bh * 2048 + q0) * 64;
  const bf16* Kb = K  + (size_t)bh * 2048 * 64;
  const bf16* Vb = Vt + (size_t)bh * 64 * 2048;

  bf16x8 qf0 = g_frag(Qb + lr * 64 + g * 8);        // d 0..31
  bf16x8 qf1 = g_frag(Qb + lr * 64 + 32 + g * 8);   // d 32..63

  f32x4 o[4] = {};
  float mrun[4], lrun[4];
#pragma unroll
  for (int r = 0; r < 4; ++r){ mrun[r] = -1e30f; lrun[r] = 0.0f; }

  for (int kv = 0; kv < 2048; kv += 64){
    // QK^T: scores for 64 keys (4 subtiles), D=64 via 2 MFMAs each
    f32x4 sc[4] = {};
#pragma unroll
    for (int t = 0; t < 4; ++t){
      const bf16* kp = Kb + (size_t)(kv + t * 16 + lr) * 64 + g * 8;
      sc[t] = MFMA16(qf0, g_frag(kp), sc[t]);
      sc[t] = MFMA16(qf1, g_frag(kp + 32), sc[t]);
    }
    // online softmax; lane's reg r = query g*4+r; 16-lane-group shuffle reduce
    float corr[4];
#pragma unroll
    for (int r = 0; r < 4; ++r){
      float s0 = sc[0][r] * 0.125f, s1 = sc[1][r] * 0.125f;
      float s2 = sc[2][r] * 0.125f, s3 = sc[3][r] * 0.125f;
      float mt = fmaxf(fmaxf(s0, s1), fmaxf(s2, s3));
      mt = fmaxf(mt, __shfl_xor(mt, 1));
      mt = fmaxf(mt, __shfl_xor(mt, 2));
      mt = fmaxf(mt, __shfl_xor(mt, 4));
      mt = fmaxf(mt, __shfl_xor(mt, 8));
      float mn = fmaxf(mrun[r], mt);
      float cr = __expf(mrun[r] - mn);
      float p0 = __expf(s0 - mn), p1 = __expf(s1 - mn);
      float p2 = __expf(s2 - mn), p3 = __expf(s3 - mn);
      float ps = p0 + p1 + p2 + p3;
      ps += __shfl_xor(ps, 1); ps += __shfl_xor(ps, 2);
      ps += __shfl_xor(ps, 4); ps += __shfl_xor(ps, 8);
      lrun[r] = lrun[r] * cr + ps;
      mrun[r] = mn;
      corr[r] = cr;
      int qrow = g * 4 + r;
      P[wid][qrow][lr]      = (bf16)p0;
      P[wid][qrow][16 + lr] = (bf16)p1;
      P[wid][qrow][32 + lr] = (bf16)p2;
      P[wid][qrow][48 + lr] = (bf16)p3;
    }
#pragma unroll
    for (int dt = 0; dt < 4; ++dt){
      o[dt][0] *= corr[0]; o[dt][1] *= corr[1];
      o[dt][2] *= corr[2]; o[dt][3] *= corr[3];
    }
    __syncthreads();   // ordering fence for cross-lane P write->read
    // PV: out(16x64) += P(16x64) * V(64x64)
#pragma unroll
    for (int kk = 0; kk < 2; ++kk){
      bf16x8 pa = lds_frag((const char*)&P[wid][lr][0] + kk * 64 + g * 16);
#pragma unroll
      for (int dt = 0; dt < 4; ++dt){
        const bf16* vp = Vb + (size_t)(dt * 16 + lr) * 2048 + kv + kk * 32 + g * 8;
        o[dt] = MFMA16(pa, g_frag(vp), o[dt]);
      }
    }
  }
  // normalize and write AO[b*2048+q][h*64+d]
  size_t row = (size_t)b * 2048 + q0 + g * 4;
#pragma unroll
  for (int dt = 0; dt < 4; ++dt){
    int col = h * 64 + dt * 16 + lr;
#pragma unroll
    for (int r = 0; r < 4; ++r)
      AO[(row + r) * 1024 + col] = (bf16)(o[dt][r] / lrun[r]);
  }
}

// ---------------------------------------------------------------------------
extern "C" void kernel_launch(void* const* d_in, const int* in_sizes, int n_in,
                              void* d_out, int out_size, void* d_ws, size_t ws_size,
                              hipStream_t stream) {
  const float* x     = (const float*)d_in[0];   // (2,2048,1024)
  const float* w_qkv = (const float*)d_in[1];   // (1024,3072)
  const float* w_out = (const float*)d_in[2];   // (1024,1024)
  float* out = (float*)d_out;                   // (2,2048,1024) f32

  char* ws = (char*)d_ws;
  const size_t MB = 1u << 20;
  unsigned* mm   = (unsigned*)(ws);              // 4 u32
  float* sintab  = (float*)(ws + 256);           // 256 KiB
  float* costab  = (float*)(ws + 256 + 262144);
  bf16* xb       = (bf16*)(ws + 1 * MB);         // 8 MiB
  bf16* wqkvT    = (bf16*)(ws + 9 * MB);         // 6 MiB  (3072 x 1024)
  bf16* woutT    = (bf16*)(ws + 15 * MB);        // 2 MiB  (1024 x 1024)
  float* qkvf    = (float*)(ws + 17 * MB);       // 48 MiB (4096 x 3072)
  bf16* Qr       = (bf16*)(ws + 65 * MB);        // 8 MiB  (32,2048,64)
  bf16* Kr       = (bf16*)(ws + 73 * MB);        // 8 MiB
  bf16* Vt       = (bf16*)(ws + 81 * MB);        // 8 MiB  (32,64,2048)
  bf16* AO       = (bf16*)(ws + 1 * MB);         // overlay on xb (xb dead after gemm1)

  init_mm<<<1, 64, 0, stream>>>(mm);
  minmax_k<<<512, 256, 0, stream>>>(w_qkv, 1024 * 3072, mm);
  minmax_k<<<512, 256, 0, stream>>>(w_out, 1024 * 1024, mm + 2);
  sincos_k<<<256, 256, 0, stream>>>(sintab, costab);
  cast_x<<<4096, 256, 0, stream>>>(x, xb, 4194304 / 4);
  dq_t<<<dim3(96, 32), dim3(32, 8), 0, stream>>>(w_qkv, wqkvT, 1024, 3072, mm);
  dq_t<<<dim3(32, 32), dim3(32, 8), 0, stream>>>(w_out, woutT, 1024, 1024, mm + 2);
  gemm_bt<<<768, 256, 0, stream>>>(xb, wqkvT, qkvf, 4096, 3072, 1024);
  rope_qk<<<8192, 256, 0, stream>>>(qkvf, sintab, costab, Qr, Kr);
  vtrans<<<1024, 256, 0, stream>>>(qkvf, Vt);
  attn_k<<<1024, 256, 0, stream>>>(Qr, Kr, Vt, AO);
  gemm_bt<<<256, 256, 0, stream>>>(AO, woutT, out, 4096, 1024, 1024);

  (void)in_sizes; (void)n_in; (void)out_size; (void)ws_size;
}

// Round 2
// 348.778 us; speedup vs baseline: 1.0103x; 1.0103x over previous
//
#include <hip/hip_runtime.h>
#include <hip/hip_bf16.h>

typedef __bf16 bf16;
typedef bf16  bf16x8 __attribute__((ext_vector_type(8)));
typedef bf16  bf16x4 __attribute__((ext_vector_type(4)));
typedef bf16  bf16x2 __attribute__((ext_vector_type(2)));
typedef float f32x4  __attribute__((ext_vector_type(4)));
typedef int   i32x4  __attribute__((ext_vector_type(4)));

#define MFMA16(a,b,c) __builtin_amdgcn_mfma_f32_16x16x32_bf16((a),(b),(c),0,0,0)

#define GLDS16(gp, lp) __builtin_amdgcn_global_load_lds( \
    (const __attribute__((address_space(1))) void*)(void*)(gp), \
    (__attribute__((address_space(3))) void*)(lp), 16, 0, 0)

static __device__ __forceinline__ bf16x8 lds_frag(const char* p){
  i32x4 v = *(const i32x4*)p;
  return __builtin_bit_cast(bf16x8, v);
}
static __device__ __forceinline__ bf16x8 g_frag(const bf16* p){
  i32x4 v = *(const i32x4*)p;
  return __builtin_bit_cast(bf16x8, v);
}
static __device__ __forceinline__ unsigned pk_bf16(float a, float b){
  bf16x2 v = { (bf16)a, (bf16)b };
  return __builtin_bit_cast(unsigned, v);
}

// ---------------- min/max reduction (order-independent -> deterministic) ---
__device__ __forceinline__ unsigned fmap(float f){
  unsigned u = __float_as_uint(f);
  return (u & 0x80000000u) ? ~u : (u | 0x80000000u);
}
__device__ __forceinline__ float funmap(unsigned m){
  unsigned u = (m & 0x80000000u) ? (m & 0x7FFFFFFFu) : ~m;
  return __uint_as_float(u);
}

__global__ void init_mm(unsigned* mm){
  if (threadIdx.x == 0){
    mm[0] = 0xFFFFFFFFu; mm[1] = 0u;   // w_qkv min,max (mapped)
    mm[2] = 0xFFFFFFFFu; mm[3] = 0u;   // w_out min,max
  }
}

__global__ void minmax_k(const float* __restrict__ w, int n, unsigned* __restrict__ mm){
  __shared__ unsigned smn[256], smx[256];
  int tid = threadIdx.x;
  unsigned lmn = 0xFFFFFFFFu, lmx = 0u;
  for (int i = blockIdx.x * blockDim.x + tid; i < n; i += gridDim.x * blockDim.x){
    unsigned u = fmap(w[i]);
    lmn = min(lmn, u); lmx = max(lmx, u);
  }
  smn[tid] = lmn; smx[tid] = lmx;
  __syncthreads();
  for (int s = 128; s > 0; s >>= 1){
    if (tid < s){
      smn[tid] = min(smn[tid], smn[tid + s]);
      smx[tid] = max(smx[tid], smx[tid + s]);
    }
    __syncthreads();
  }
  if (tid == 0){ atomicMin(&mm[0], smn[0]); atomicMax(&mm[1], smx[0]); }
}

// ------------- fake-quant dequant + transpose + cast to bf16 ---------------
__global__ void dq_t(const float* __restrict__ w, bf16* __restrict__ wt,
                     int R, int C, const unsigned* __restrict__ mm){
  __shared__ float t[32][33];
  float xmin = funmap(mm[0]);
  float xmax = funmap(mm[1]);
  float scale = (xmax - xmin) / 255.0f;
  float denom = scale + 1e-8f;
  int ct = blockIdx.x * 32, rt = blockIdx.y * 32;
  int tx = threadIdx.x, ty = threadIdx.y;   // 32 x 8
#pragma unroll
  for (int p = 0; p < 4; ++p){
    int r = rt + p * 8 + ty;
    float x = w[(size_t)r * C + ct + tx];
    float q = rintf(fminf(fmaxf((x - xmin) / denom, 0.0f), 255.0f));
    t[p * 8 + ty][tx] = q * scale + xmin;
  }
  __syncthreads();
#pragma unroll
  for (int p = 0; p < 4; ++p){
    int c = p * 8 + ty;
    wt[(size_t)(ct + c) * R + rt + tx] = (bf16)t[tx][c];
  }
}

// ---------------- cast x (f32) -> bf16, vectorized x4 ----------------------
__global__ void cast_x(const float* __restrict__ x, bf16* __restrict__ xb, int n4){
  int i = blockIdx.x * 256 + threadIdx.x;
  if (i < n4){
    f32x4 v = *(const f32x4*)(x + (size_t)i * 4);
    bf16x4 o = { (bf16)v.x, (bf16)v.y, (bf16)v.z, (bf16)v.w };
    *(bf16x4*)(xb + (size_t)i * 4) = o;
  }
}

// ---------------- rope tables ----------------------------------------------
__global__ void sincos_k(float* __restrict__ sintab, float* __restrict__ costab){
  int idx = blockIdx.x * 256 + threadIdx.x;   // s*32 + i, 65536 total
  int i = idx & 31, s = idx >> 5;
  float invf = powf(10000.0f, -(float)i / 32.0f);
  float fr = (float)s * invf;
  sintab[idx] = sinf(fr);
  costab[idx] = cosf(fr);
}

// ------------- rope + reshape QKV(f32) -> Qr,Kr (B,H,S,D) bf16 -------------
// Q is pre-scaled by 1/sqrt(D) = 0.125 (exact in bf16) so attn skips it.
__global__ void rope_qk(const float* __restrict__ qkv,
                        const float* __restrict__ sintab, const float* __restrict__ costab,
                        bf16* __restrict__ Qr, bf16* __restrict__ Kr){
  int idx = blockIdx.x * 256 + threadIdx.x;   // (bh*2048 + s)*32 + i
  int i  = idx & 31;
  int s  = (idx >> 5) & 2047;
  int bh = idx >> 16;
  int b = bh >> 4, h = bh & 15;
  const float* row = qkv + (size_t)(b * 2048 + s) * 3072 + h * 64;
  float q1 = row[i],        q2 = row[32 + i];
  float k1 = row[1024 + i], k2 = row[1024 + 32 + i];
  float sn = sintab[s * 32 + i], cs = costab[s * 32 + i];
  size_t o = ((size_t)bh * 2048 + s) * 64 + i;
  Qr[o]      = (bf16)((q1 * cs - q2 * sn) * 0.125f);
  Qr[o + 32] = (bf16)((q1 * sn + q2 * cs) * 0.125f);
  Kr[o]      = (bf16)(k1 * cs - k2 * sn);
  Kr[o + 32] = (bf16)(k1 * sn + k2 * cs);
}

// ------------- V transpose: QKV(f32) -> Vt (B,H,D,S) bf16 ------------------
__global__ void vtrans(const float* __restrict__ qkv, bf16* __restrict__ Vt){
  __shared__ float t[64][65];
  int bh = blockIdx.x >> 5;
  int st = (blockIdx.x & 31) * 64;
  int b = bh >> 4, h = bh & 15;
  int tx = threadIdx.x & 63, ty4 = threadIdx.x >> 6;
#pragma unroll
  for (int p = 0; p < 16; ++p){
    int s = p * 4 + ty4;
    t[s][tx] = qkv[(size_t)(b * 2048 + st + s) * 3072 + 2048 + h * 64 + tx];
  }
  __syncthreads();
#pragma unroll
  for (int p = 0; p < 16; ++p){
    int d = p * 4 + ty4;
    Vt[((size_t)bh * 64 + d) * 2048 + st + tx] = (bf16)t[tx][d];
  }
}

// ---------------- bf16 MFMA GEMM, C = A * Bt^T (unchanged) -----------------
__global__ __launch_bounds__(256, 2) void gemm_bt(
    const bf16* __restrict__ A, const bf16* __restrict__ Bt,
    float* __restrict__ C, int M, int N, int K)
{
  __shared__ __align__(16) char lds[32768];
  int nbx = N >> 7;
  int bid = blockIdx.x;
  int nwg = gridDim.x;
  if ((nwg & 7) == 0){ int q = nwg >> 3; bid = (bid & 7) * q + (bid >> 3); }
  int row0 = (bid / nbx) << 7;
  int col0 = (bid % nbx) << 7;
  int tid = threadIdx.x, lane = tid & 63, wid = tid >> 6;
  int wr = (wid >> 1) * 64, wc = (wid & 1) * 64;
  int lr = lane & 15, g = lane >> 4;

  int aoff[2][4], boff[2][4];
#pragma unroll
  for (int kk = 0; kk < 2; ++kk){
#pragma unroll
    for (int m = 0; m < 4; ++m){
      int ra = wr + m * 16 + lr;
      aoff[kk][m] = ra * 128 + ((((kk * 4 + g) ^ ((ra >> 1) & 7))) << 4);
      int rb = wc + m * 16 + lr;
      boff[kk][m] = 16384 + rb * 128 + ((((kk * 4 + g) ^ ((rb >> 1) & 7))) << 4);
    }
  }

  const bf16* pA[4]; const bf16* pB[4]; int loff[4];
#pragma unroll
  for (int is = 0; is < 4; ++is){
    int f = is * 4096 + wid * 1024 + lane * 16;
    int r = f >> 7, c = (f >> 4) & 7;
    int cg = c ^ ((r >> 1) & 7);
    pA[is] = A  + (size_t)(row0 + r) * K + cg * 8;
    pB[is] = Bt + (size_t)(col0 + r) * K + cg * 8;
    loff[is] = is * 4096 + wid * 1024;
  }

  f32x4 acc[4][4] = {};
  for (int kt = 0; kt < K; kt += 64){
    __syncthreads();
#pragma unroll
    for (int is = 0; is < 4; ++is){
      GLDS16(pA[is] + kt, lds + loff[is]);
      GLDS16(pB[is] + kt, lds + 16384 + loff[is]);
    }
    __syncthreads();
#pragma unroll
    for (int kk = 0; kk < 2; ++kk){
      bf16x8 af[4], bfb[4];
#pragma unroll
      for (int m = 0; m < 4; ++m) af[m] = lds_frag(lds + aoff[kk][m]);
#pragma unroll
      for (int n = 0; n < 4; ++n) bfb[n] = lds_frag(lds + boff[kk][n]);
#pragma unroll
      for (int m = 0; m < 4; ++m)
#pragma unroll
        for (int n = 0; n < 4; ++n)
          acc[m][n] = MFMA16(af[m], bfb[n], acc[m][n]);
    }
  }

#pragma unroll
  for (int m = 0; m < 4; ++m){
    int row = row0 + wr + m * 16 + g * 4;
#pragma unroll
    for (int n = 0; n < 4; ++n){
      int col = col0 + wc + n * 16 + lr;
      float* cp = C + (size_t)row * N + col;
#pragma unroll
      for (int r = 0; r < 4; ++r)
        cp[(size_t)r * N] = acc[m][n][r];
    }
  }
}

// ---------------- flash attention, swapped-operand, barrier-free -----------
// grid: 4096 1-wave blocks; each wave owns 16 queries of one (b,h).
// QK^T computed as mfma(K,Q) -> S[k][q]: one QUERY per lane (q = lane&15),
// softmax is in-lane (15 VALU) + 2 shuffles. PV as mfma(V^T,P) -> O[d][q],
// so m/l/corr stay per-lane scalars. P redistributed lane->lane via shfl.
// No LDS, no barriers.
__global__ __launch_bounds__(64, 4) void attn_k(
    const bf16* __restrict__ Q, const bf16* __restrict__ K,
    const bf16* __restrict__ Vt, bf16* __restrict__ AO)
{
  int bid = blockIdx.x;
  bid = (bid & 7) * 512 + (bid >> 3);     // XCD chunking: 4 whole heads per XCD
  int bh = bid >> 7;                      // 128 q-tiles per (b,h)
  int qt = bid & 127;
  int b = bh >> 4, h = bh & 15;
  int lane = threadIdx.x;
  int lr = lane & 15, g = lane >> 4;
  int q0 = qt * 16;

  const bf16* Qb = Q  + ((size_t)bh * 2048 + q0) * 64;
  const bf16* Kb = K  + (size_t)bh * 2048 * 64;
  const bf16* Vb = Vt + (size_t)bh * 64 * 2048;

  // B-frag: lane holds Q row lr (query q0+lr), d-slice g*8 (pre-scaled by 0.125)
  bf16x8 qf0 = g_frag(Qb + lr * 64 + g * 8);
  bf16x8 qf1 = g_frag(Qb + lr * 64 + 32 + g * 8);

  f32x4 o[4] = {};
  float mrun = -1e30f, lrun = 0.0f;

  int srcA = (g & 1) * 32 + lr;   // lane holding keys (g&1)*8+0..3 of my t
  int srcB = srcA + 16;           // keys (g&1)*8+4..7
  int hi = g & 2;                 // my t = 2kk + (g>>1)

  for (int kv = 0; kv < 2048; kv += 64){
    // ---- QK^T: S[k][q] for 64 keys; lane gets keys {t*16+g*4+r}, query lr
    bf16x8 kf[4][2];
#pragma unroll
    for (int t = 0; t < 4; ++t){
      const bf16* kp = Kb + (size_t)(kv + t * 16 + lr) * 64 + g * 8;
      kf[t][0] = g_frag(kp);
      kf[t][1] = g_frag(kp + 32);
    }
    f32x4 sc[4] = {};
#pragma unroll
    for (int t = 0; t < 4; ++t){
      sc[t] = MFMA16(kf[t][0], qf0, sc[t]);
      sc[t] = MFMA16(kf[t][1], qf1, sc[t]);
    }
    // ---- V loads for kk=0 issue now; latency hides under softmax
    bf16x8 vf0[4];
#pragma unroll
    for (int dt = 0; dt < 4; ++dt)
      vf0[dt] = g_frag(Vb + (size_t)(dt * 16 + lr) * 2048 + kv + g * 8);

    // ---- online softmax, per-lane scalar state (query q0+lr)
    float mt = -1e30f;
#pragma unroll
    for (int t = 0; t < 4; ++t){
      float a = fmaxf(fmaxf(sc[t][0], sc[t][1]), fmaxf(sc[t][2], sc[t][3]));
      mt = fmaxf(mt, a);
    }
    mt = fmaxf(mt, __shfl_xor(mt, 16));
    mt = fmaxf(mt, __shfl_xor(mt, 32));
    float mn = fmaxf(mrun, mt);
    float cr = __expf(mrun - mn);
    float p[4][4];
    float ps = 0.0f;
#pragma unroll
    for (int t = 0; t < 4; ++t){
#pragma unroll
      for (int r = 0; r < 4; ++r){
        p[t][r] = __expf(sc[t][r] - mn);
        ps += p[t][r];
      }
    }
    ps += __shfl_xor(ps, 16);
    ps += __shfl_xor(ps, 32);
    lrun = lrun * cr + ps;
    mrun = mn;

    // pack to bf16 pairs: u[t][j] = keys {t*16+g*4+2j, +2j+1} (query lr)
    unsigned u[4][2];
#pragma unroll
    for (int t = 0; t < 4; ++t){
      u[t][0] = pk_bf16(p[t][0], p[t][1]);
      u[t][1] = pk_bf16(p[t][2], p[t][3]);
    }

    // rescale accumulator by per-lane scalar
#pragma unroll
    for (int dt = 0; dt < 4; ++dt){
      o[dt][0] *= cr; o[dt][1] *= cr; o[dt][2] *= cr; o[dt][3] *= cr;
    }

    // ---- V loads for kk=1
    bf16x8 vf1[4];
#pragma unroll
    for (int dt = 0; dt < 4; ++dt)
      vf1[dt] = g_frag(Vb + (size_t)(dt * 16 + lr) * 2048 + kv + 32 + g * 8);

    // ---- redistribute P into B-frag layout and do PV: O[d][q]
#pragma unroll
    for (int kk = 0; kk < 2; ++kk){
      unsigned w0a = __shfl(u[2 * kk][0], srcA), w0b = __shfl(u[2 * kk + 1][0], srcA);
      unsigned w1a = __shfl(u[2 * kk][1], srcA), w1b = __shfl(u[2 * kk + 1][1], srcA);
      unsigned w2a = __shfl(u[2 * kk][0], srcB), w2b = __shfl(u[2 * kk + 1][0], srcB);
      unsigned w3a = __shfl(u[2 * kk][1], srcB), w3b = __shfl(u[2 * kk + 1][1], srcB);
      i32x4 wv = { (int)(hi ? w0b : w0a), (int)(hi ? w1b : w1a),
                   (int)(hi ? w2b : w2a), (int)(hi ? w3b : w3a) };
      bf16x8 pf = __builtin_bit_cast(bf16x8, wv);
#pragma unroll
      for (int dt = 0; dt < 4; ++dt)
        o[dt] = MFMA16(kk ? vf1[dt] : vf0[dt], pf, o[dt]);
    }
  }

  // ---- normalize (per-lane scalar) and write AO[b*2048+q][h*64+d]
  float inv = 1.0f / lrun;
  size_t row = (size_t)b * 2048 + q0 + lr;
#pragma unroll
  for (int dt = 0; dt < 4; ++dt){
    bf16x4 ov = { (bf16)(o[dt][0] * inv), (bf16)(o[dt][1] * inv),
                  (bf16)(o[dt][2] * inv), (bf16)(o[dt][3] * inv) };
    *(bf16x4*)(AO + row * 1024 + h * 64 + dt * 16 + g * 4) = ov;
  }
}

// ---------------------------------------------------------------------------
extern "C" void kernel_launch(void* const* d_in, const int* in_sizes, int n_in,
                              void* d_out, int out_size, void* d_ws, size_t ws_size,
                              hipStream_t stream) {
  const float* x     = (const float*)d_in[0];   // (2,2048,1024)
  const float* w_qkv = (const float*)d_in[1];   // (1024,3072)
  const float* w_out = (const float*)d_in[2];   // (1024,1024)
  float* out = (float*)d_out;                   // (2,2048,1024) f32

  char* ws = (char*)d_ws;
  const size_t MB = 1u << 20;
  unsigned* mm   = (unsigned*)(ws);              // 4 u32
  float* sintab  = (float*)(ws + 256);           // 256 KiB
  float* costab  = (float*)(ws + 256 + 262144);
  bf16* xb       = (bf16*)(ws + 1 * MB);         // 8 MiB
  bf16* wqkvT    = (bf16*)(ws + 9 * MB);         // 6 MiB  (3072 x 1024)
  bf16* woutT    = (bf16*)(ws + 15 * MB);        // 2 MiB  (1024 x 1024)
  float* qkvf    = (float*)(ws + 17 * MB);       // 48 MiB (4096 x 3072)
  bf16* Qr       = (bf16*)(ws + 65 * MB);        // 8 MiB  (32,2048,64)
  bf16* Kr       = (bf16*)(ws + 73 * MB);        // 8 MiB
  bf16* Vt       = (bf16*)(ws + 81 * MB);        // 8 MiB  (32,64,2048)
  bf16* AO       = (bf16*)(ws + 1 * MB);         // overlay on xb (dead after gemm1)

  init_mm<<<1, 64, 0, stream>>>(mm);
  minmax_k<<<512, 256, 0, stream>>>(w_qkv, 1024 * 3072, mm);
  minmax_k<<<512, 256, 0, stream>>>(w_out, 1024 * 1024, mm + 2);
  sincos_k<<<256, 256, 0, stream>>>(sintab, costab);
  cast_x<<<4096, 256, 0, stream>>>(x, xb, 4194304 / 4);
  dq_t<<<dim3(96, 32), dim3(32, 8), 0, stream>>>(w_qkv, wqkvT, 1024, 3072, mm);
  dq_t<<<dim3(32, 32), dim3(32, 8), 0, stream>>>(w_out, woutT, 1024, 1024, mm + 2);
  gemm_bt<<<768, 256, 0, stream>>>(xb, wqkvT, qkvf, 4096, 3072, 1024);
  rope_qk<<<8192, 256, 0, stream>>>(qkvf, sintab, costab, Qr, Kr);
  vtrans<<<1024, 256, 0, stream>>>(qkvf, Vt);
  attn_k<<<4096, 64, 0, stream>>>(Qr, Kr, Vt, AO);
  gemm_bt<<<256, 256, 0, stream>>>(AO, woutT, out, 4096, 1024, 1024);

  (void)in_sizes; (void)n_in; (void)out_size; (void)ws_size;
}

// Round 3
// 239.240 us; speedup vs baseline: 1.4729x; 1.4579x over previous
//
#include <hip/hip_runtime.h>
#include <hip/hip_bf16.h>

typedef __bf16 bf16;
typedef bf16  bf16x8 __attribute__((ext_vector_type(8)));
typedef bf16  bf16x4 __attribute__((ext_vector_type(4)));
typedef bf16  bf16x2 __attribute__((ext_vector_type(2)));
typedef float f32x4  __attribute__((ext_vector_type(4)));
typedef float f32x16 __attribute__((ext_vector_type(16)));
typedef int   i32x4  __attribute__((ext_vector_type(4)));

#define MFMA16(a,b,c) __builtin_amdgcn_mfma_f32_16x16x32_bf16((a),(b),(c),0,0,0)
#define MFMA32(a,b,c) __builtin_amdgcn_mfma_f32_32x32x16_bf16((a),(b),(c),0,0,0)

#define GLDS16(gp, lp) __builtin_amdgcn_global_load_lds( \
    (const __attribute__((address_space(1))) void*)(void*)(gp), \
    (__attribute__((address_space(3))) void*)(lp), 16, 0, 0)

static __device__ __forceinline__ bf16x8 lds_frag(const char* p){
  i32x4 v = *(const i32x4*)p;
  return __builtin_bit_cast(bf16x8, v);
}
static __device__ __forceinline__ bf16x8 g_frag(const bf16* p){
  i32x4 v = *(const i32x4*)p;
  return __builtin_bit_cast(bf16x8, v);
}
static __device__ __forceinline__ unsigned pk_bf16(float a, float b){
  bf16x2 v = { (bf16)a, (bf16)b };
  return __builtin_bit_cast(unsigned, v);
}
// swap upper 32 lanes of a with lower 32 lanes of b (gfx950)
static __device__ __forceinline__ void p32swap(unsigned &a, unsigned &b){
  asm("v_permlane32_swap_b32 %0, %1" : "+v"(a), "+v"(b));
}

// ---------------- min/max reduction (order-independent -> deterministic) ---
__device__ __forceinline__ unsigned fmap(float f){
  unsigned u = __float_as_uint(f);
  return (u & 0x80000000u) ? ~u : (u | 0x80000000u);
}
__device__ __forceinline__ float funmap(unsigned m){
  unsigned u = (m & 0x80000000u) ? (m & 0x7FFFFFFFu) : ~m;
  return __uint_as_float(u);
}

__global__ void init_mm(unsigned* mm){
  if (threadIdx.x == 0){
    mm[0] = 0xFFFFFFFFu; mm[1] = 0u;   // w_qkv min,max (mapped)
    mm[2] = 0xFFFFFFFFu; mm[3] = 0u;   // w_out min,max
  }
}

__global__ void minmax_k(const float* __restrict__ w, int n, unsigned* __restrict__ mm){
  __shared__ unsigned smn[256], smx[256];
  int tid = threadIdx.x;
  unsigned lmn = 0xFFFFFFFFu, lmx = 0u;
  for (int i = blockIdx.x * blockDim.x + tid; i < n; i += gridDim.x * blockDim.x){
    unsigned u = fmap(w[i]);
    lmn = min(lmn, u); lmx = max(lmx, u);
  }
  smn[tid] = lmn; smx[tid] = lmx;
  __syncthreads();
  for (int s = 128; s > 0; s >>= 1){
    if (tid < s){
      smn[tid] = min(smn[tid], smn[tid + s]);
      smx[tid] = max(smx[tid], smx[tid + s]);
    }
    __syncthreads();
  }
  if (tid == 0){ atomicMin(&mm[0], smn[0]); atomicMax(&mm[1], smx[0]); }
}

// ------------- fake-quant dequant + transpose + cast to bf16 ---------------
__global__ void dq_t(const float* __restrict__ w, bf16* __restrict__ wt,
                     int R, int C, const unsigned* __restrict__ mm){
  __shared__ float t[32][33];
  float xmin = funmap(mm[0]);
  float xmax = funmap(mm[1]);
  float scale = (xmax - xmin) / 255.0f;
  float denom = scale + 1e-8f;
  int ct = blockIdx.x * 32, rt = blockIdx.y * 32;
  int tx = threadIdx.x, ty = threadIdx.y;   // 32 x 8
#pragma unroll
  for (int p = 0; p < 4; ++p){
    int r = rt + p * 8 + ty;
    float x = w[(size_t)r * C + ct + tx];
    float q = rintf(fminf(fmaxf((x - xmin) / denom, 0.0f), 255.0f));
    t[p * 8 + ty][tx] = q * scale + xmin;
  }
  __syncthreads();
#pragma unroll
  for (int p = 0; p < 4; ++p){
    int c = p * 8 + ty;
    wt[(size_t)(ct + c) * R + rt + tx] = (bf16)t[tx][c];
  }
}

// ---------------- cast x (f32) -> bf16, vectorized x4 ----------------------
__global__ void cast_x(const float* __restrict__ x, bf16* __restrict__ xb, int n4){
  int i = blockIdx.x * 256 + threadIdx.x;
  if (i < n4){
    f32x4 v = *(const f32x4*)(x + (size_t)i * 4);
    bf16x4 o = { (bf16)v.x, (bf16)v.y, (bf16)v.z, (bf16)v.w };
    *(bf16x4*)(xb + (size_t)i * 4) = o;
  }
}

// ---------------- rope tables ----------------------------------------------
__global__ void sincos_k(float* __restrict__ sintab, float* __restrict__ costab){
  int idx = blockIdx.x * 256 + threadIdx.x;   // s*32 + i, 65536 total
  int i = idx & 31, s = idx >> 5;
  float invf = powf(10000.0f, -(float)i / 32.0f);
  float fr = (float)s * invf;
  sintab[idx] = sinf(fr);
  costab[idx] = cosf(fr);
}

// ------------- rope + reshape QKV(f32) -> Qr,Kr (B,H,S,D) bf16 -------------
// Q pre-scaled by (1/sqrt(D)) * log2(e) so attn uses exp2 directly.
__global__ void rope_qk(const float* __restrict__ qkv,
                        const float* __restrict__ sintab, const float* __restrict__ costab,
                        bf16* __restrict__ Qr, bf16* __restrict__ Kr){
  int idx = blockIdx.x * 256 + threadIdx.x;   // (bh*2048 + s)*32 + i
  int i  = idx & 31;
  int s  = (idx >> 5) & 2047;
  int bh = idx >> 16;
  int b = bh >> 4, h = bh & 15;
  const float QS = 0.18033688011f;   // 0.125 * log2(e)
  const float* row = qkv + (size_t)(b * 2048 + s) * 3072 + h * 64;
  float q1 = row[i],        q2 = row[32 + i];
  float k1 = row[1024 + i], k2 = row[1024 + 32 + i];
  float sn = sintab[s * 32 + i], cs = costab[s * 32 + i];
  size_t o = ((size_t)bh * 2048 + s) * 64 + i;
  Qr[o]      = (bf16)((q1 * cs - q2 * sn) * QS);
  Qr[o + 32] = (bf16)((q1 * sn + q2 * cs) * QS);
  Kr[o]      = (bf16)(k1 * cs - k2 * sn);
  Kr[o + 32] = (bf16)(k1 * sn + k2 * cs);
}

// ------------- V transpose: QKV(f32) -> Vt (B,H,D,S) bf16 ------------------
__global__ void vtrans(const float* __restrict__ qkv, bf16* __restrict__ Vt){
  __shared__ float t[64][65];
  int bh = blockIdx.x >> 5;
  int st = (blockIdx.x & 31) * 64;
  int b = bh >> 4, h = bh & 15;
  int tx = threadIdx.x & 63, ty4 = threadIdx.x >> 6;
#pragma unroll
  for (int p = 0; p < 16; ++p){
    int s = p * 4 + ty4;
    t[s][tx] = qkv[(size_t)(b * 2048 + st + s) * 3072 + 2048 + h * 64 + tx];
  }
  __syncthreads();
#pragma unroll
  for (int p = 0; p < 16; ++p){
    int d = p * 4 + ty4;
    Vt[((size_t)bh * 64 + d) * 2048 + st + tx] = (bf16)t[tx][d];
  }
}

// ---------------- bf16 MFMA GEMM, C = A * Bt^T (unchanged) -----------------
__global__ __launch_bounds__(256, 2) void gemm_bt(
    const bf16* __restrict__ A, const bf16* __restrict__ Bt,
    float* __restrict__ C, int M, int N, int K)
{
  __shared__ __align__(16) char lds[32768];
  int nbx = N >> 7;
  int bid = blockIdx.x;
  int nwg = gridDim.x;
  if ((nwg & 7) == 0){ int q = nwg >> 3; bid = (bid & 7) * q + (bid >> 3); }
  int row0 = (bid / nbx) << 7;
  int col0 = (bid % nbx) << 7;
  int tid = threadIdx.x, lane = tid & 63, wid = tid >> 6;
  int wr = (wid >> 1) * 64, wc = (wid & 1) * 64;
  int lr = lane & 15, g = lane >> 4;

  int aoff[2][4], boff[2][4];
#pragma unroll
  for (int kk = 0; kk < 2; ++kk){
#pragma unroll
    for (int m = 0; m < 4; ++m){
      int ra = wr + m * 16 + lr;
      aoff[kk][m] = ra * 128 + ((((kk * 4 + g) ^ ((ra >> 1) & 7))) << 4);
      int rb = wc + m * 16 + lr;
      boff[kk][m] = 16384 + rb * 128 + ((((kk * 4 + g) ^ ((rb >> 1) & 7))) << 4);
    }
  }

  const bf16* pA[4]; const bf16* pB[4]; int loff[4];
#pragma unroll
  for (int is = 0; is < 4; ++is){
    int f = is * 4096 + wid * 1024 + lane * 16;
    int r = f >> 7, c = (f >> 4) & 7;
    int cg = c ^ ((r >> 1) & 7);
    pA[is] = A  + (size_t)(row0 + r) * K + cg * 8;
    pB[is] = Bt + (size_t)(col0 + r) * K + cg * 8;
    loff[is] = is * 4096 + wid * 1024;
  }

  f32x4 acc[4][4] = {};
  for (int kt = 0; kt < K; kt += 64){
    __syncthreads();
#pragma unroll
    for (int is = 0; is < 4; ++is){
      GLDS16(pA[is] + kt, lds + loff[is]);
      GLDS16(pB[is] + kt, lds + 16384 + loff[is]);
    }
    __syncthreads();
#pragma unroll
    for (int kk = 0; kk < 2; ++kk){
      bf16x8 af[4], bfb[4];
#pragma unroll
      for (int m = 0; m < 4; ++m) af[m] = lds_frag(lds + aoff[kk][m]);
#pragma unroll
      for (int n = 0; n < 4; ++n) bfb[n] = lds_frag(lds + boff[kk][n]);
#pragma unroll
      for (int m = 0; m < 4; ++m)
#pragma unroll
        for (int n = 0; n < 4; ++n)
          acc[m][n] = MFMA16(af[m], bfb[n], acc[m][n]);
    }
  }

#pragma unroll
  for (int m = 0; m < 4; ++m){
    int row = row0 + wr + m * 16 + g * 4;
#pragma unroll
    for (int n = 0; n < 4; ++n){
      int col = col0 + wc + n * 16 + lr;
      float* cp = C + (size_t)row * N + col;
#pragma unroll
      for (int r = 0; r < 4; ++r)
        cp[(size_t)r * N] = acc[m][n][r];
    }
  }
}

// ---------------- flash attention, 32x32 MFMA, permlane P-redistribute -----
// grid: 512 blocks x 4 waves; wave owns 32 queries of one (b,h).
// QK^T as mfma32(K,Q): S[key][q], q = lane&31; per-lane softmax over 16 regs
// + one xor-32 shuffle. P->B-frag fix-up: 8 cvt_pk + 4 v_permlane32_swap per
// 32 keys (pure VALU, no DS). K/V register double-buffered (~200 VGPRs).
#define LOADK(KF, kvoff) do { _Pragma("unroll") \
    for (int t = 0; t < 4; ++t) \
      KF[t] = g_frag(Kb + (size_t)((kvoff) + l31) * 64 + t * 16 + hi8); } while(0)

#define LOADV(VF, kvoff) do { _Pragma("unroll") \
    for (int u = 0; u < 4; ++u) \
      VF[u] = g_frag(Vb + (size_t)((u & 1) * 32 + l31) * 2048 + (kvoff) + (u >> 1) * 16 + hi8); } while(0)

#define ATTN_TILE(KF, VF) do {                                               \
    f32x16 sc = {};                                                          \
    _Pragma("unroll")                                                        \
    for (int t = 0; t < 4; ++t) sc = MFMA32(KF[t], qf[t], sc);               \
    float mt = -1e30f;                                                       \
    _Pragma("unroll")                                                        \
    for (int r = 0; r < 16; ++r) mt = fmaxf(mt, sc[r]);                      \
    mt = fmaxf(mt, __shfl_xor(mt, 32));                                      \
    float mn = fmaxf(mrun, mt);                                              \
    float cr = __builtin_amdgcn_exp2f(mrun - mn);                            \
    float p[16]; float ps = 0.0f;                                            \
    _Pragma("unroll")                                                        \
    for (int r = 0; r < 16; ++r){                                            \
      p[r] = __builtin_amdgcn_exp2f(sc[r] - mn); ps += p[r]; }               \
    ps += __shfl_xor(ps, 32);                                                \
    lrun = lrun * cr + ps;  mrun = mn;                                       \
    _Pragma("unroll")                                                        \
    for (int r = 0; r < 16; ++r){ o0[r] *= cr; o1[r] *= cr; }                \
    _Pragma("unroll")                                                        \
    for (int kh = 0; kh < 2; ++kh){                                          \
      unsigned a0 = pk_bf16(p[kh*8+0], p[kh*8+1]);                           \
      unsigned a1 = pk_bf16(p[kh*8+2], p[kh*8+3]);                           \
      unsigned b0 = pk_bf16(p[kh*8+4], p[kh*8+5]);                           \
      unsigned b1 = pk_bf16(p[kh*8+6], p[kh*8+7]);                           \
      p32swap(a0, b0); p32swap(a1, b1);                                      \
      i32x4 wv = { (int)a0, (int)a1, (int)b0, (int)b1 };                     \
      bf16x8 pf = __builtin_bit_cast(bf16x8, wv);                            \
      o0 = MFMA32(VF[kh*2+0], pf, o0);                                       \
      o1 = MFMA32(VF[kh*2+1], pf, o1);                                       \
    }                                                                        \
  } while(0)

__global__ __launch_bounds__(256, 2) void attn_k(
    const bf16* __restrict__ Q, const bf16* __restrict__ K,
    const bf16* __restrict__ Vt, bf16* __restrict__ AO)
{
  int bid = blockIdx.x;
  bid = (bid & 7) * 64 + (bid >> 3);      // XCD chunking: 2 heads per XCD
  int bh = bid >> 4;                      // 16 blocks per head
  int qblk = bid & 15;
  int b = bh >> 4, h = bh & 15;
  int tid = threadIdx.x, lane = tid & 63, wid = tid >> 6;
  int l31 = lane & 31, hi8 = (lane >> 5) * 8;
  int q0 = qblk * 128 + wid * 32;

  const bf16* Qb = Q  + ((size_t)bh * 2048 + q0) * 64;
  const bf16* Kb = K  + (size_t)bh * 2048 * 64;
  const bf16* Vb = Vt + (size_t)bh * 64 * 2048;

  // Q B-frags: col = q (lane&31), k(d) = t*16 + hi*8 + j   (pre-scaled)
  bf16x8 qf[4];
#pragma unroll
  for (int t = 0; t < 4; ++t)
    qf[t] = g_frag(Qb + (size_t)l31 * 64 + t * 16 + hi8);

  f32x16 o0 = {}, o1 = {};     // O[d 0..31][q], O[d 32..63][q]
  float mrun = -1e30f, lrun = 0.0f;

  bf16x8 k0f[4], k1f[4], v0f[4], v1f[4];
  LOADK(k0f, 0); LOADV(v0f, 0);

  for (int kv = 0; kv < 2048; kv += 64){
    LOADK(k1f, kv + 32); LOADV(v1f, kv + 32);
    ATTN_TILE(k0f, v0f);
    if (kv + 64 < 2048){ LOADK(k0f, kv + 64); LOADV(v0f, kv + 64); }
    ATTN_TILE(k1f, v1f);
  }

  // epilogue: o reg r -> d = 8*(r>>2) + 4*hi + (r&3) (+32 for o1); row = q
  float inv = 1.0f / lrun;
  size_t row = (size_t)b * 2048 + q0 + l31;
  bf16* op = AO + row * 1024 + h * 64 + (hi8 >> 1);
#pragma unroll
  for (int qd = 0; qd < 4; ++qd){
    bf16x4 w0 = { (bf16)(o0[qd*4+0]*inv), (bf16)(o0[qd*4+1]*inv),
                  (bf16)(o0[qd*4+2]*inv), (bf16)(o0[qd*4+3]*inv) };
    *(bf16x4*)(op + qd * 8) = w0;
    bf16x4 w1 = { (bf16)(o1[qd*4+0]*inv), (bf16)(o1[qd*4+1]*inv),
                  (bf16)(o1[qd*4+2]*inv), (bf16)(o1[qd*4+3]*inv) };
    *(bf16x4*)(op + 32 + qd * 8) = w1;
  }
}

// ---------------------------------------------------------------------------
extern "C" void kernel_launch(void* const* d_in, const int* in_sizes, int n_in,
                              void* d_out, int out_size, void* d_ws, size_t ws_size,
                              hipStream_t stream) {
  const float* x     = (const float*)d_in[0];   // (2,2048,1024)
  const float* w_qkv = (const float*)d_in[1];   // (1024,3072)
  const float* w_out = (const float*)d_in[2];   // (1024,1024)
  float* out = (float*)d_out;                   // (2,2048,1024) f32

  char* ws = (char*)d_ws;
  const size_t MB = 1u << 20;
  unsigned* mm   = (unsigned*)(ws);              // 4 u32
  float* sintab  = (float*)(ws + 256);           // 256 KiB
  float* costab  = (float*)(ws + 256 + 262144);
  bf16* xb       = (bf16*)(ws + 1 * MB);         // 8 MiB
  bf16* wqkvT    = (bf16*)(ws + 9 * MB);         // 6 MiB  (3072 x 1024)
  bf16* woutT    = (bf16*)(ws + 15 * MB);        // 2 MiB  (1024 x 1024)
  float* qkvf    = (float*)(ws + 17 * MB);       // 48 MiB (4096 x 3072)
  bf16* Qr       = (bf16*)(ws + 65 * MB);        // 8 MiB  (32,2048,64)
  bf16* Kr       = (bf16*)(ws + 73 * MB);        // 8 MiB
  bf16* Vt       = (bf16*)(ws + 81 * MB);        // 8 MiB  (32,64,2048)
  bf16* AO       = (bf16*)(ws + 1 * MB);         // overlay on xb (dead after gemm1)

  init_mm<<<1, 64, 0, stream>>>(mm);
  minmax_k<<<512, 256, 0, stream>>>(w_qkv, 1024 * 3072, mm);
  minmax_k<<<512, 256, 0, stream>>>(w_out, 1024 * 1024, mm + 2);
  sincos_k<<<256, 256, 0, stream>>>(sintab, costab);
  cast_x<<<4096, 256, 0, stream>>>(x, xb, 4194304 / 4);
  dq_t<<<dim3(96, 32), dim3(32, 8), 0, stream>>>(w_qkv, wqkvT, 1024, 3072, mm);
  dq_t<<<dim3(32, 32), dim3(32, 8), 0, stream>>>(w_out, woutT, 1024, 1024, mm + 2);
  gemm_bt<<<768, 256, 0, stream>>>(xb, wqkvT, qkvf, 4096, 3072, 1024);
  rope_qk<<<8192, 256, 0, stream>>>(qkvf, sintab, costab, Qr, Kr);
  vtrans<<<1024, 256, 0, stream>>>(qkvf, Vt);
  attn_k<<<512, 256, 0, stream>>>(Qr, Kr, Vt, AO);
  gemm_bt<<<256, 256, 0, stream>>>(AO, woutT, out, 4096, 1024, 1024);

  (void)in_sizes; (void)n_in; (void)out_size; (void)ws_size;
}